// Round 1
// baseline (958.072 us; speedup 1.0000x reference)
//
#include <hip/hip_runtime.h>
#include <math.h>

#define TPB 256

// problem sizes
constexpr int BSZ = 256, TL = 3, NV = 90, SV = 65, CH = 45;
constexpr int NS = NV*SV;            // 5850
constexpr int NP = TL*BSZ;           // 768 (t,b) pairs, q = t*256+b
constexpr int NM = NV*NV;            // 8100
constexpr int CCOL = TL*CH;          // 135 combined (t',o) columns
constexpr int CONV_H = 88, CONV_W = 43, FEAT = CONV_H*CONV_W; // 3784
constexpr int FLATD = TL*FEAT;       // 11352

// workspace layout (float offsets). Z overlays Y+L region (freed before k_Z).
constexpr size_t OFF_CSUM = 0;                       // 256
constexpr size_t OFF_LAM  = 256;                     // 768
constexpr size_t OFF_BEFF = 1024;                    // 2
constexpr size_t OFF_M    = 1056;                    // 2048
constexpr size_t OFF_MA   = 3104;                    // 2048
constexpr size_t OFF_WEFF = 5152;                    // 22704
constexpr size_t OFF_Y    = 32768;                   // 768*5850 = 4,492,800
constexpr size_t OFF_L    = OFF_Y  + (size_t)NP*NS;  // 6,220,800
constexpr size_t OFF_LT   = OFF_L  + (size_t)NP*NM;
constexpr size_t OFF_T2   = OFF_LT + (size_t)NP*NM;
constexpr size_t OFF_Z    = OFF_Y;                   // 9,331,200 (fits in Y+L = 10,713,600)
constexpr size_t OFF_H    = OFF_T2 + (size_t)NP*NM;  // 768*12150 = 9,331,200
constexpr size_t OFF_X    = OFF_H  + (size_t)NP*TL*NV*CH; // 256*11352
// total ≈ 35.4M floats ≈ 142 MB

// ---------------- uncertainty head: csum[b] = sum_j sigmoid(u[3b+j]) ----------------
__global__ __launch_bounds__(TPB) void k_csum(const float* __restrict__ fdata,
                                              const float* __restrict__ unw,
                                              const float* __restrict__ unb,
                                              float* __restrict__ csum)
{
    __shared__ float red[TPB];
    const int b = blockIdx.x, tid = threadIdx.x;
    float s = 0.f;
    for (int j = 0; j < 3; ++j) {
        int r = 3*b + j;                       // flat row in tlen-major order
        const float* row = fdata + ((size_t)(r & 255)*TL + (r >> 8))*NS;
        float p = 0.f;
        for (int i = tid; i < NS; i += TPB) p += row[i]*unw[i];
        red[tid] = p; __syncthreads();
        if (tid < 128) red[tid] += red[tid+128]; __syncthreads();
        if (tid < 64)  red[tid] += red[tid+64];  __syncthreads();
        if (tid < 64) {
            float x = red[tid];
            for (int o = 32; o >= 1; o >>= 1) x += __shfl_down(x, o);
            if (tid == 0) red[0] = x;
        }
        __syncthreads();
        float u = red[0] + unb[0];
        __syncthreads();
        s += 1.f/(1.f + expf(-u));
    }
    if (tid == 0) csum[b] = s;
}

// ---------------- per-(t,b) row normalization: y = (x-mean)/(||xc||+1e-6) ----------------
__global__ __launch_bounds__(TPB) void k_norm(const float* __restrict__ fdata, float* __restrict__ Y)
{
    const int q = blockIdx.x, tid = threadIdx.x;
    const int t = q >> 8, b = q & 255;
    const float* xp = fdata + ((size_t)b*TL + t)*NS;
    float* yp = Y + (size_t)q*NS;
    const int wave = tid >> 6, lane = tid & 63;
    for (int nrow = wave; nrow < NV; nrow += 4) {
        const float* row = xp + nrow*SV;
        float s1 = 0.f, s2 = 0.f;
        for (int s = lane; s < SV; s += 64) { float v = row[s]; s1 += v; s2 += v*v; }
        for (int o = 1; o < 64; o <<= 1) { s1 += __shfl_xor(s1, o); s2 += __shfl_xor(s2, o); }
        float mean = s1 / SV;
        float var  = s2 - SV*mean*mean;
        float inv  = 1.f / (sqrtf(fmaxf(var, 0.f)) + 1e-6f);
        for (int s = lane; s < SV; s += 64) yp[nrow*SV + s] = (row[s] - mean)*inv;
    }
}

// ---------------- corr -> W -> L = diag(rowsum W) - W ----------------
__global__ __launch_bounds__(TPB) void k_corrL(const float* __restrict__ Y, float* __restrict__ Lg)
{
    __shared__ __align__(16) float yl[NV][68];   // pad 65 -> 68 (17 float4), zero tail
    __shared__ float Wl[NM];
    __shared__ float Dl[NV];
    const int q = blockIdx.x, tid = threadIdx.x;
    const float* yp = Y + (size_t)q*NS;
    for (int idx = tid; idx < NS; idx += TPB) yl[idx/SV][idx%SV] = yp[idx];
    for (int idx = tid; idx < NV*3; idx += TPB) yl[idx/3][SV + idx%3] = 0.f;
    __syncthreads();
    for (int idx = tid; idx < NM; idx += TPB) {
        int nn = idx / NV, mm = idx % NV;
        const float4* a  = reinterpret_cast<const float4*>(&yl[nn][0]);
        const float4* bb = reinterpret_cast<const float4*>(&yl[mm][0]);
        float acc = 0.f;
        #pragma unroll
        for (int ii = 0; ii < 17; ++ii) {
            float4 x = a[ii], y4 = bb[ii];
            acc += x.x*y4.x + x.y*y4.y + x.z*y4.z + x.w*y4.w;
        }
        Wl[idx] = (acc + 1.f)*0.5f;
    }
    __syncthreads();
    if (tid < NV) {
        float d = 0.f;
        for (int mm = 0; mm < NV; ++mm) d += Wl[tid*NV + mm];
        Dl[tid] = d;
    }
    __syncthreads();
    for (int idx = tid; idx < NM; idx += TPB) {
        int nn = idx / NV, mm = idx % NV;
        Lg[(size_t)q*NM + idx] = ((nn == mm) ? Dl[nn] : 0.f) - Wl[idx];
    }
}

// ---------------- max eigenvalue by shifted power iteration ----------------
__global__ __launch_bounds__(TPB) void k_eig(const float* __restrict__ Lg, float* __restrict__ lam)
{
    __shared__ float Ll[NM];
    __shared__ float vl[NV], wl[NV];
    __shared__ float red1[TPB], red2[TPB];
    __shared__ float sh0, sh1;
    const int tid = threadIdx.x;
    const int q = blockIdx.x;
    for (int idx = tid; idx < NM; idx += TPB) Ll[idx] = Lg[(size_t)q*NM + idx];
    if (tid < NV) vl[tid] = sinf(1.3f*tid + 0.5f) + 0.05f;   // generic start vector
    __syncthreads();

    const int n = tid >> 1, hh = tid & 1;

    auto matvec = [&](float sigma) {
        float p = 0.f;
        if (tid < 2*NV) {
            const float* row = &Ll[n*NV + 45*hh];
            const float* vv  = &vl[45*hh];
            #pragma unroll 9
            for (int i = 0; i < 45; ++i) p += row[i]*vv[i];
        }
        p += __shfl_xor(p, 1);
        if (tid < 2*NV && hh == 0) wl[n] = p - sigma*vl[n];
        __syncthreads();
    };
    auto reduce2 = [&](float a, float b, float& s1, float& s2) {
        red1[tid] = a; red2[tid] = b; __syncthreads();
        if (tid < 128) { red1[tid] += red1[tid+128]; red2[tid] += red2[tid+128]; } __syncthreads();
        if (tid < 64)  { red1[tid] += red1[tid+64];  red2[tid] += red2[tid+64];  } __syncthreads();
        if (tid < 64) {
            float x1 = red1[tid], x2 = red2[tid];
            for (int o = 32; o >= 1; o >>= 1) { x1 += __shfl_down(x1, o); x2 += __shfl_down(x2, o); }
            if (tid == 0) { sh0 = x1; sh1 = x2; }
        }
        __syncthreads();
        s1 = sh0; s2 = sh1;
        __syncthreads();
    };
    auto renorm = [&]() {
        float wv = (tid < NV) ? wl[tid] : 0.f;
        float s1, s2; reduce2(wv, wv*wv, s1, s2);
        float mean = s1 * (1.f/NV);                 // deflate the 1-vector (eig 0)
        float ns = s2 - NV*mean*mean;
        float rn = rsqrtf(fmaxf(ns, 1e-30f));
        if (tid < NV) vl[tid] = (wl[tid] - mean)*rn;
        __syncthreads();
    };

    if (tid < NV) wl[tid] = vl[tid];
    __syncthreads();
    renorm();

    for (int it = 0; it < 16; ++it) { matvec(0.f); renorm(); }
    float sigma;
    {
        matvec(0.f);
        float a = (tid < NV) ? vl[tid]*wl[tid] : 0.f;
        float b = (tid < NV) ? vl[tid]*vl[tid] : 0.f;
        float s1, s2; reduce2(a, b, s1, s2);
        sigma = 0.45f*(s1/s2);                       // Rayleigh <= lam1 -> shift always safe
    }
    for (int it = 0; it < 100; ++it) { matvec(sigma); renorm(); }
    {
        matvec(0.f);
        float a = (tid < NV) ? vl[tid]*wl[tid] : 0.f;
        float b = (tid < NV) ? vl[tid]*vl[tid] : 0.f;
        float s1, s2; reduce2(a, b, s1, s2);
        if (tid == 0) lam[q] = s1/s2;
    }
}

// ---------------- Lt = 2L/lam - I ; T2 = 2*Lt*Lt - I (elementwise) ----------------
__global__ __launch_bounds__(TPB) void k_cheb(const float* __restrict__ Lg, const float* __restrict__ lam,
                                              float* __restrict__ Lt, float* __restrict__ T2)
{
    size_t idx = (size_t)blockIdx.x*TPB + threadIdx.x;
    if (idx >= (size_t)NP*NM) return;
    int q = (int)(idx / NM); int r = (int)(idx % NM);
    int nn = r / NV, mm = r % NV;
    float I = (nn == mm) ? 1.f : 0.f;
    float lt = 2.f*Lg[idx]/lam[q] - I;
    Lt[idx] = lt;
    T2[idx] = 2.f*lt*lt - I;
}

// ---------------- Z[k][b][m][t'*45+o] = sum_s fdata[b,t',m,s] * theta[k,s,o] ----------------
__global__ __launch_bounds__(TPB) void k_Z(const float* __restrict__ fdata,
                                           const float* __restrict__ theta, float* __restrict__ Z)
{
    __shared__ float fl[NV*SV];
    __shared__ float thl[3*SV*CH];
    const int g = blockIdx.x, tid = threadIdx.x;
    const int b = g/3, tp = g%3;
    const float* fp = fdata + ((size_t)b*TL + tp)*NS;
    for (int idx = tid; idx < NS; idx += TPB) fl[idx] = fp[idx];
    for (int idx = tid; idx < 3*SV*CH; idx += TPB) thl[idx] = theta[idx];
    __syncthreads();
    for (int idx = tid; idx < NV*CCOL; idx += TPB) {
        int m = idx / CCOL, r = idx % CCOL, k = r / CH, o = r % CH;
        float acc = 0.f;
        const float* fr = &fl[m*SV];
        const float* th = &thl[k*SV*CH + o];
        #pragma unroll 13
        for (int s = 0; s < SV; ++s) acc += fr[s]*th[s*CH];
        Z[((size_t)(k*BSZ + b)*NV + m)*CCOL + tp*CH + o] = acc;
    }
}

// ---------------- h[t,b,t',n,o] = relu(Z0 + Lt@Z1 + T2@Z2) ----------------
__global__ __launch_bounds__(TPB) void k_h(const float* __restrict__ Lt, const float* __restrict__ T2g,
                                           const float* __restrict__ Z, float* __restrict__ h)
{
    __shared__ __align__(16) float Al[NV][48];       // Lt rows n0..n0+44, transposed [m][nl]
    __shared__ __align__(16) float Bl[NV][48];       // T2
    __shared__ __align__(16) float Zl[2][NV][136];   // Z1,Z2 (col pad 135->136)
    const int tid = threadIdx.x;
    const int blk = blockIdx.x, half = blk & 1, q = blk >> 1;
    const int b = q & 255;
    const int n0 = half*45;
    for (int idx = tid; idx < 45*NV; idx += TPB) {
        int nl = idx / NV, m = idx % NV;
        size_t base = (size_t)q*NM + (size_t)(n0 + nl)*NV + m;
        Al[m][nl] = Lt[base];
        Bl[m][nl] = T2g[base];
    }
    for (int idx = tid; idx < NV*3; idx += TPB) { int m = idx/3; int jj = 45 + idx%3; Al[m][jj] = 0.f; Bl[m][jj] = 0.f; }
    for (int idx = tid; idx < NV*CCOL; idx += TPB) {
        int m = idx / CCOL, c = idx % CCOL;
        Zl[0][m][c] = Z[((size_t)(BSZ   + b)*NV + m)*CCOL + c];
        Zl[1][m][c] = Z[((size_t)(2*BSZ + b)*NV + m)*CCOL + c];
    }
    for (int idx = tid; idx < 2*NV; idx += TPB) Zl[idx/NV][idx%NV][135] = 0.f;
    __syncthreads();
    const float* Z0 = Z + (size_t)b*NV*CCOL;
    for (int pass = 0; pass < 2; ++pass) {
        int tile = tid + pass*TPB;
        if (tile >= 12*34) continue;
        int tn = tile / 34, tc = tile % 34;
        int nl = tn*4, c0 = tc*4;
        float acc[4][4] = {};
        for (int m = 0; m < NV; ++m) {
            float4 a4 = *reinterpret_cast<const float4*>(&Al[m][nl]);
            float4 b4 = *reinterpret_cast<const float4*>(&Bl[m][nl]);
            float4 z1 = *reinterpret_cast<const float4*>(&Zl[0][m][c0]);
            float4 z2 = *reinterpret_cast<const float4*>(&Zl[1][m][c0]);
            float av[4]  = {a4.x, a4.y, a4.z, a4.w};
            float bv[4]  = {b4.x, b4.y, b4.z, b4.w};
            float z1v[4] = {z1.x, z1.y, z1.z, z1.w};
            float z2v[4] = {z2.x, z2.y, z2.z, z2.w};
            #pragma unroll
            for (int i2 = 0; i2 < 4; ++i2)
                #pragma unroll
                for (int j2 = 0; j2 < 4; ++j2)
                    acc[i2][j2] += av[i2]*z1v[j2] + bv[i2]*z2v[j2];
        }
        #pragma unroll
        for (int i2 = 0; i2 < 4; ++i2) {
            int nloc = nl + i2;
            if (nloc < 45) {
                int nglob = n0 + nloc;
                #pragma unroll
                for (int j2 = 0; j2 < 4; ++j2) {
                    int c = c0 + j2;
                    if (c < CCOL) {
                        float v = acc[i2][j2] + Z0[(size_t)nglob*CCOL + c];
                        v = fmaxf(v, 0.f);
                        int tp = c / CH, oo = c % CH;
                        h[(size_t)q*(TL*NV*CH) + (size_t)tp*(NV*CH) + (size_t)nglob*CH + oo] = v;
                    }
                }
            }
        }
    }
}

// ---------------- conv 3x3x3 -> relu -> 1x1 -> scale by csum, write x ----------------
__global__ __launch_bounds__(TPB) void k_conv(const float* __restrict__ h,
    const float* __restrict__ tw, const float* __restrict__ tb,
    const float* __restrict__ ow, const float* __restrict__ ob,
    const float* __restrict__ csum, float* __restrict__ x)
{
    __shared__ float hl[TL][NV][CH];
    const int q = blockIdx.x, tid = threadIdx.x;
    const int t = q >> 8, b = q & 255;
    const float* hp = h + (size_t)q*(TL*NV*CH);
    for (int idx = tid; idx < TL*NV*CH; idx += TPB) ((float*)hl)[idx] = hp[idx];
    __syncthreads();
    const float cs  = csum[b];
    const float obv = ob[0];
    for (int pix = tid; pix < FEAT; pix += TPB) {
        int i = pix / CONV_W, j = pix % CONV_W;
        float p[TL][3][3];
        #pragma unroll
        for (int tp = 0; tp < TL; ++tp)
            #pragma unroll
            for (int di = 0; di < 3; ++di)
                #pragma unroll
                for (int dj = 0; dj < 3; ++dj)
                    p[tp][di][dj] = hl[tp][i+di][j+dj];
        float o = 0.f;
        #pragma unroll
        for (int f = 0; f < 10; ++f) {
            float c = tb[f];
            #pragma unroll
            for (int tp = 0; tp < TL; ++tp)
                #pragma unroll
                for (int di = 0; di < 3; ++di)
                    #pragma unroll
                    for (int dj = 0; dj < 3; ++dj)
                        c += p[tp][di][dj]*tw[((f*TL + tp)*3 + di)*3 + dj];
            o += fmaxf(c, 0.f)*ow[f];
        }
        x[(size_t)b*FLATD + t*FEAT + pix] = (o + obv)*cs;
    }
}

// ---------------- FC collapse: M = W2 D2 W3 ; Ma = D1 M ----------------
__global__ void k_eff1(const float* __restrict__ W2, const float* __restrict__ g2,
                       const float* __restrict__ W3, const float* __restrict__ g1,
                       float* __restrict__ M, float* __restrict__ Ma)
{
    int gid = blockIdx.x*TPB + threadIdx.x;
    if (gid >= 2048) return;
    int i = gid >> 1, c = gid & 1;
    const float rs = rsqrtf(1.f + 1e-5f);
    float acc = 0.f;
    for (int j = 0; j < 256; ++j) acc += W2[i*256 + j]*(g2[j]*rs)*W3[j*2 + c];
    M[gid]  = acc;
    Ma[gid] = acc*(g1[i]*rs);
}

__global__ void k_effb(const float* __restrict__ M, const float* __restrict__ W3,
                       const float* __restrict__ b1, const float* __restrict__ bb1, const float* __restrict__ g1,
                       const float* __restrict__ b2, const float* __restrict__ bb2, const float* __restrict__ g2,
                       const float* __restrict__ b3, float* __restrict__ beff)
{
    __shared__ float r0[TPB], r1[TPB];
    int tid = threadIdx.x;
    const float rs = rsqrtf(1.f + 1e-5f);
    float a0 = 0.f, a1 = 0.f;
    for (int i = tid; i < 1024; i += TPB) {
        float wv = b1[i]*(g1[i]*rs) + bb1[i];
        a0 += wv*M[2*i]; a1 += wv*M[2*i+1];
    }
    for (int j = tid; j < 256; j += TPB) {
        float wv = b2[j]*(g2[j]*rs) + bb2[j];
        a0 += wv*W3[2*j]; a1 += wv*W3[2*j+1];
    }
    r0[tid] = a0; r1[tid] = a1; __syncthreads();
    if (tid < 128) { r0[tid] += r0[tid+128]; r1[tid] += r1[tid+128]; } __syncthreads();
    if (tid < 64)  { r0[tid] += r0[tid+64];  r1[tid] += r1[tid+64];  } __syncthreads();
    if (tid < 64) {
        float x0 = r0[tid], x1 = r1[tid];
        for (int o = 32; o >= 1; o >>= 1) { x0 += __shfl_down(x0, o); x1 += __shfl_down(x1, o); }
        if (tid == 0) { beff[0] = x0 + b3[0]; beff[1] = x1 + b3[1]; }
    }
}

// ---------------- Weff[r][c] = sum_i W1[r][i] * Ma[i][c]  (wave per row) ----------------
__global__ void k_eff2(const float* __restrict__ W1, const float* __restrict__ Ma, float* __restrict__ Weff)
{
    int tid = threadIdx.x;
    int r = blockIdx.x*4 + (tid >> 6);
    int lane = tid & 63;
    if (r >= FLATD) return;
    const float* wrow = W1 + (size_t)r*1024;
    float a0 = 0.f, a1 = 0.f;
    for (int i = lane; i < 1024; i += 64) {
        float w = wrow[i];
        a0 += w*Ma[2*i]; a1 += w*Ma[2*i+1];
    }
    for (int o = 32; o >= 1; o >>= 1) { a0 += __shfl_down(a0, o); a1 += __shfl_down(a1, o); }
    if (lane == 0) { Weff[2*r] = a0; Weff[2*r+1] = a1; }
}

// ---------------- logits + softmax ----------------
__global__ void k_logits(const float* __restrict__ x, const float* __restrict__ Weff,
                         const float* __restrict__ beff, float* __restrict__ out)
{
    __shared__ float r0[TPB], r1[TPB];
    int b = blockIdx.x, tid = threadIdx.x;
    const float* xr = x + (size_t)b*FLATD;
    float a0 = 0.f, a1 = 0.f;
    for (int i = tid; i < FLATD; i += TPB) {
        float v = xr[i];
        a0 += v*Weff[2*i]; a1 += v*Weff[2*i+1];
    }
    r0[tid] = a0; r1[tid] = a1; __syncthreads();
    if (tid < 128) { r0[tid] += r0[tid+128]; r1[tid] += r1[tid+128]; } __syncthreads();
    if (tid < 64)  { r0[tid] += r0[tid+64];  r1[tid] += r1[tid+64];  } __syncthreads();
    if (tid < 64) {
        float x0 = r0[tid], x1 = r1[tid];
        for (int o = 32; o >= 1; o >>= 1) { x0 += __shfl_down(x0, o); x1 += __shfl_down(x1, o); }
        if (tid == 0) {
            float l0 = x0 + beff[0], l1 = x1 + beff[1];
            float mx = fmaxf(l0, l1);
            float e0 = expf(l0 - mx), e1 = expf(l1 - mx);
            float s = e0 + e1;
            out[2*b]     = e0/s;
            out[2*b + 1] = e1/s;
        }
    }
}

extern "C" void kernel_launch(void* const* d_in, const int* in_sizes, int n_in,
                              void* d_out, int out_size, void* d_ws, size_t ws_size,
                              hipStream_t stream)
{
    const float* fdata = (const float*)d_in[0];
    const float* un_w  = (const float*)d_in[1];
    const float* un_b  = (const float*)d_in[2];
    const float* theta = (const float*)d_in[3];
    const float* tcw   = (const float*)d_in[4];
    const float* tcb   = (const float*)d_in[5];
    const float* ocw   = (const float*)d_in[6];
    const float* ocb   = (const float*)d_in[7];
    const float* l1w   = (const float*)d_in[8];
    const float* l1b   = (const float*)d_in[9];
    const float* bn1g  = (const float*)d_in[10];
    const float* bn1b  = (const float*)d_in[11];
    const float* l2w   = (const float*)d_in[12];
    const float* l2b   = (const float*)d_in[13];
    const float* bn2g  = (const float*)d_in[14];
    const float* bn2b  = (const float*)d_in[15];
    const float* l3w   = (const float*)d_in[16];
    const float* l3b   = (const float*)d_in[17];

    float* ws   = (float*)d_ws;
    float* csum = ws + OFF_CSUM;
    float* lam  = ws + OFF_LAM;
    float* beff = ws + OFF_BEFF;
    float* M    = ws + OFF_M;
    float* Ma   = ws + OFF_MA;
    float* Weff = ws + OFF_WEFF;
    float* Y    = ws + OFF_Y;
    float* L    = ws + OFF_L;
    float* Lt   = ws + OFF_LT;
    float* T2   = ws + OFF_T2;
    float* Z    = ws + OFF_Z;
    float* H    = ws + OFF_H;
    float* X    = ws + OFF_X;
    float* out  = (float*)d_out;

    k_csum <<<BSZ, TPB, 0, stream>>>(fdata, un_w, un_b, csum);
    k_norm <<<NP, TPB, 0, stream>>>(fdata, Y);
    k_corrL<<<NP, TPB, 0, stream>>>(Y, L);
    k_eig  <<<NP, TPB, 0, stream>>>(L, lam);
    k_cheb <<<(int)(((size_t)NP*NM + TPB - 1)/TPB), TPB, 0, stream>>>(L, lam, Lt, T2);
    k_Z    <<<BSZ*TL, TPB, 0, stream>>>(fdata, theta, Z);   // overlays Y/L (both dead now)
    k_h    <<<NP*2, TPB, 0, stream>>>(Lt, T2, Z, H);
    k_conv <<<NP, TPB, 0, stream>>>(H, tcw, tcb, ocw, ocb, csum, X);
    k_eff1 <<<8, TPB, 0, stream>>>(l2w, bn2g, l3w, bn1g, M, Ma);
    k_effb <<<1, TPB, 0, stream>>>(M, l3w, l1b, bn1b, bn1g, l2b, bn2b, bn2g, l3b, beff);
    k_eff2 <<<(FLATD + 3)/4, TPB, 0, stream>>>(l1w, Ma, Weff);
    k_logits<<<BSZ, TPB, 0, stream>>>(X, Weff, beff, out);
}

// Round 2
// 557.928 us; speedup vs baseline: 1.7172x; 1.7172x over previous
//
#include <hip/hip_runtime.h>
#include <math.h>

#define TPB 256

// problem sizes
constexpr int BSZ = 256, TL = 3, NV = 90, SV = 65, CH = 45;
constexpr int NS = NV*SV;            // 5850
constexpr int NP = TL*BSZ;           // 768 (t,b) pairs, q = t*256+b
constexpr int NM = NV*NV;            // 8100
constexpr int CCOL = TL*CH;          // 135 combined (t',o) columns
constexpr int ZLD = 136;             // padded Z row stride (16B-aligned float4 rows)
constexpr int CONV_H = 88, CONV_W = 43, FEAT = CONV_H*CONV_W; // 3784
constexpr int FLATD = TL*FEAT;       // 11352

// workspace layout (float offsets)
constexpr size_t OFF_CSUM = 0;                        // 256
constexpr size_t OFF_LAM  = 256;                      // 768
constexpr size_t OFF_BEFF = 1024;                     // 2
constexpr size_t OFF_M    = 1056;                     // 2048
constexpr size_t OFF_MA   = 3104;                     // 2048
constexpr size_t OFF_WEFF = 5152;                     // 22704
constexpr size_t OFF_L    = 32768;                    // 768*8100 = 6,220,800
constexpr size_t OFF_Z    = 6291456;                  // 3*256*90*136 = 9,400,320
constexpr size_t OFF_X    = 15728640;                 // 256*11352 = 2,906,112

// ============================================================================
// k_prep: fused row-normalize + pearson corr -> L (+ global write) + power-iter
// eigenvalue + uncertainty-head partial (atomicAdd into csum).
// One block per q = t*256 + b.
// ============================================================================
__global__ __launch_bounds__(TPB) void k_prep(const float* __restrict__ fdata,
    const float* __restrict__ unw, const float* __restrict__ unb,
    float* __restrict__ Lout, float* __restrict__ lamOut, float* __restrict__ csum)
{
    __shared__ float yT[65*96];      // swizzled col-major normalized y  (24,960 B)
    __shared__ float Ll[90*92];      // W then L, padded stride 92       (33,120 B)
    __shared__ float Dl[NV];
    __shared__ float vbuf[2][92];    // power-iteration double buffer (pad [90..91]=0)
    __shared__ float red[TPB];
    __shared__ float sh0, sh1;

    const int q = blockIdx.x, tid = threadIdx.x;
    const int t = q >> 8, b = q & 255;
    const float* xp = fdata + ((size_t)b*TL + t)*NS;
    const int wave = tid >> 6, lane = tid & 63;

    // ---- phase 1: per-row normalize into yT (swizzled), csum partial ----
    float up = 0.f;
    for (int n = wave; n < NV; n += 4) {
        const float* row = xp + n*SV;
        float va = row[lane];                          // s = lane (0..63 < 65)
        float vb = (lane == 0) ? row[64] : 0.f;        // s = 64
        up += va*unw[n*SV + lane];
        if (lane == 0) up += vb*unw[n*SV + 64];
        float s1 = va + vb, s2 = va*va + vb*vb;
        #pragma unroll
        for (int o = 1; o < 64; o <<= 1) { s1 += __shfl_xor(s1, o); s2 += __shfl_xor(s2, o); }
        float mean = s1 / SV;
        float var  = s2 - SV*mean*mean;
        float inv  = 1.f / (sqrtf(fmaxf(var, 0.f)) + 1e-6f);
        // swizzled store: col block (n/4 + s) % 24
        yT[lane*96 + (((n >> 2) + lane) % 24)*4 + (n & 3)] = (va - mean)*inv;
        if (lane == 0)
            yT[64*96 + (((n >> 2) + 64) % 24)*4 + (n & 3)] = (vb - mean)*inv;
    }
    red[tid] = up; __syncthreads();
    if (tid < 128) red[tid] += red[tid+128]; __syncthreads();
    if (tid < 64)  red[tid] += red[tid+64];  __syncthreads();
    if (tid < 64) {
        float x = red[tid];
        #pragma unroll
        for (int o = 32; o >= 1; o >>= 1) x += __shfl_down(x, o);
        if (tid == 0) {
            float u = x + unb[0];
            atomicAdd(csum + (q/3), 1.f/(1.f + expf(-u)));
        }
    }
    __syncthreads();

    // ---- phase 2: corr tiles (4x4 register blocking) -> W into Ll ----
    for (int tile = tid; tile < 529; tile += TPB) {     // 23x23 tiles of 4x4
        int tr = tile / 23, tc = tile - tr*23;
        int n0 = 4*tr, m0 = 4*tc;
        int ca = tr, cb = tc;                            // (n0>>2 + s) % 24 trackers
        float acc[4][4] = {};
        for (int s = 0; s < SV; ++s) {
            const float* base = &yT[s*96];
            float4 a4 = *(const float4*)(base + 4*ca);
            float4 b4 = *(const float4*)(base + 4*cb);
            float av[4] = {a4.x, a4.y, a4.z, a4.w};
            float bv[4] = {b4.x, b4.y, b4.z, b4.w};
            #pragma unroll
            for (int i = 0; i < 4; ++i)
                #pragma unroll
                for (int j = 0; j < 4; ++j) acc[i][j] += av[i]*bv[j];
            if (++ca == 24) ca = 0;
            if (++cb == 24) cb = 0;
        }
        #pragma unroll
        for (int i = 0; i < 4; ++i) {
            int n = n0 + i; if (n >= NV) break;
            #pragma unroll
            for (int j = 0; j < 4; ++j) {
                int m = m0 + j;
                if (m < NV) Ll[n*92 + m] = (acc[i][j] + 1.f)*0.5f;
            }
        }
    }
    __syncthreads();

    // ---- phase 3: row sums D ----
    if (tid < NV) {
        float d = 0.f;
        for (int m = 0; m < NV; ++m) d += Ll[tid*92 + m];
        Dl[tid] = d;
    }
    __syncthreads();

    // ---- phase 4: L = diag(D) - W  (in place + global) ----
    for (int idx = tid; idx < NM; idx += TPB) {
        int n = idx / NV, m = idx - n*NV;
        float v = ((n == m) ? Dl[n] : 0.f) - Ll[n*92 + m];
        Ll[n*92 + m] = v;
        Lout[(size_t)q*NM + idx] = v;
    }
    __syncthreads();

    // ---- phase 5: shifted power iteration, L rows cached in registers ----
    float r[90];
    if (tid < NV) {
        const float4* row4 = (const float4*)&Ll[tid*92];
        #pragma unroll
        for (int j = 0; j < 22; ++j) {
            float4 x = row4[j];
            r[4*j] = x.x; r[4*j+1] = x.y; r[4*j+2] = x.z; r[4*j+3] = x.w;
        }
        r[88] = Ll[tid*92 + 88]; r[89] = Ll[tid*92 + 89];
        vbuf[0][tid] = sinf(1.3f*tid + 0.5f) + 0.05f;
    }
    if (tid >= 90 && tid < 92) { vbuf[0][tid] = 0.f; vbuf[1][tid] = 0.f; }
    __syncthreads();

    int cur = 0;
    auto step = [&](float sigma) {
        if (tid < NV) {
            const float4* v4 = (const float4*)&vbuf[cur][0];
            float p = 0.f;
            #pragma unroll
            for (int j = 0; j < 22; ++j) {
                float4 x = v4[j];
                p += r[4*j]*x.x + r[4*j+1]*x.y + r[4*j+2]*x.z + r[4*j+3]*x.w;
            }
            p += r[88]*vbuf[cur][88] + r[89]*vbuf[cur][89];
            vbuf[cur^1][tid] = p - sigma*vbuf[cur][tid];
        }
        __syncthreads();
        cur ^= 1;
    };
    auto renorm = [&]() {
        if (tid < 64) {
            float xa = vbuf[cur][tid], xb = (tid < 26) ? vbuf[cur][64+tid] : 0.f;
            float a1 = xa + xb, a2 = xa*xa + xb*xb;
            #pragma unroll
            for (int o = 1; o < 64; o <<= 1) { a1 += __shfl_xor(a1, o); a2 += __shfl_xor(a2, o); }
            if (tid == 0) { sh0 = a1; sh1 = a2; }
        }
        __syncthreads();
        float mean = sh0*(1.f/90.f);
        float ns   = sh1 - 90.f*mean*mean;
        float rn   = rsqrtf(fmaxf(ns, 1e-30f));
        if (tid < NV) vbuf[cur][tid] = (vbuf[cur][tid] - mean)*rn;
        __syncthreads();
    };
    auto dot_vw = [&]() {   // sum over 90 of vbuf[cur^1]*vbuf[cur] -> sh0
        if (tid < 64) {
            float p = vbuf[cur][tid]*vbuf[cur^1][tid];
            if (tid < 26) p += vbuf[cur][64+tid]*vbuf[cur^1][64+tid];
            #pragma unroll
            for (int o = 1; o < 64; o <<= 1) p += __shfl_xor(p, o);
            if (tid == 0) sh0 = p;
        }
        __syncthreads();
    };

    for (int it = 0; it < 8; ++it) step(0.f);
    renorm();
    step(0.f);                       // w = L v  in vbuf[cur], v in vbuf[cur^1]
    cur ^= 1;                        // cur = v, cur^1 = w
    dot_vw();
    float sigma = 0.45f*sh0;
    __syncthreads();
    if (tid < NV) vbuf[cur^1][tid] -= sigma*vbuf[cur][tid];   // seed shifted iterate
    __syncthreads();
    cur ^= 1;
    for (int it = 0; it < 88; ++it) {
        step(sigma);
        if ((it & 7) == 7) renorm();
    }
    renorm();
    step(0.f);
    cur ^= 1;                        // cur = v (unit), cur^1 = L v
    dot_vw();
    if (tid == 0) lamOut[q] = sh0;
}

// ============================================================================
// k_Z: Z[k][b][m][tp*45+o] = sum_s fdata[b,tp,m,s] * theta[k,s,o]
// outer-product form; Z rows padded to 136 (zeroed pad col 135).
// ============================================================================
__global__ __launch_bounds__(TPB) void k_Z(const float* __restrict__ fdata,
                                           const float* __restrict__ theta,
                                           float* __restrict__ Z)
{
    __shared__ float flT[65*96];         // transposed fdata slice [s][m], pad 96
    __shared__ float thl[3*65*48];       // theta [k][s][o], pad 48

    const int g = blockIdx.x, tid = threadIdx.x;
    const int b = g/3, tp = g - 3*b;
    const float* fp = fdata + ((size_t)b*TL + tp)*NS;

    for (int idx = tid; idx < 65*96; idx += TPB) {
        int s = idx / 96, m = idx - s*96;
        flT[idx] = (m < NV) ? fp[m*SV + s] : 0.f;
    }
    for (int idx = tid; idx < 3*65*48; idx += TPB) {
        int k = idx / (65*48), rr = idx - k*(65*48);
        int s = rr / 48, o = rr - s*48;
        thl[idx] = (o < CH) ? theta[(k*SV + s)*CH + o] : 0.f;
    }
    __syncthreads();

    // tiles: 36 ct (k*12+ot) x 12 mt (8 rows) = 432
    for (int tile = tid; tile < 432; tile += TPB) {
        int ct = tile / 12, mt = tile - ct*12;
        int k = ct / 12, ot = ct - k*12;
        int o0 = 4*ot, m0 = 8*mt;
        float acc[8][4] = {};
        const float4* thp = (const float4*)&thl[(k*65)*48 + o0];
        const float4* fp4 = (const float4*)&flT[m0];
        for (int s = 0; s < SV; ++s) {
            float4 tv = thp[s*12];
            float4 fa = fp4[s*24], fb = fp4[s*24 + 1];
            float fv[8] = {fa.x, fa.y, fa.z, fa.w, fb.x, fb.y, fb.z, fb.w};
            #pragma unroll
            for (int i = 0; i < 8; ++i) {
                acc[i][0] += fv[i]*tv.x; acc[i][1] += fv[i]*tv.y;
                acc[i][2] += fv[i]*tv.z; acc[i][3] += fv[i]*tv.w;
            }
        }
        #pragma unroll
        for (int i = 0; i < 8; ++i) {
            int m = m0 + i; if (m >= NV) break;
            #pragma unroll
            for (int j = 0; j < 4; ++j) {
                int o = o0 + j;
                if (o < CH)
                    Z[((size_t)(k*BSZ + b)*NV + m)*ZLD + tp*CH + o] = acc[i][j];
            }
        }
    }
    if (tp == 2) {   // zero pad column 135 (read by float4 GEMM streams)
        for (int idx = tid; idx < 3*NV; idx += TPB) {
            int k = idx / NV, m = idx - k*NV;
            Z[((size_t)(k*BSZ + b)*NV + m)*ZLD + 135] = 0.f;
        }
    }
}

// ============================================================================
// k_hc: fused  h = relu(Z0 + Lt@Z1 + (2Lt^2)@Z2 - Z2)  ->  3x3x3 conv -> relu
//       -> 1x1 conv -> *csum -> X.   Lt built on the fly from L and lambda.
// One block per q; LDS = union(A-tile 33KB, h-tile 48.6KB).
// ============================================================================
__global__ __launch_bounds__(TPB) void k_hc(const float* __restrict__ L,
    const float* __restrict__ lam, const float* __restrict__ Z,
    const float* __restrict__ tw, const float* __restrict__ tb,
    const float* __restrict__ ow, const float* __restrict__ ob,
    const float* __restrict__ csum, float* __restrict__ X)
{
    __shared__ float smem[12160];        // 48,640 B (A: 8280 fl; h: 12150 fl)
    const int q = blockIdx.x, tid = threadIdx.x;
    const int t = q >> 8, b = q & 255;
    const float il2 = 2.0f / lam[q];

    // stage A = Lt (symmetric), stride 92
    for (int idx = tid; idx < NM; idx += TPB) {
        int i = idx / NV, j = idx - i*NV;
        smem[i*92 + j] = il2 * L[(size_t)q*NM + idx] - ((i == j) ? 1.f : 0.f);
    }
    __syncthreads();

    // GEMM: per-thread 6 rows x 8 cols; 255 active threads (15 x 17 tiles)
    float acc[6][8];
    const int tn = tid / 17, tc = tid - tn*17;
    const int n0 = 6*tn, c0 = 8*tc;
    const bool act = (tid < 255);
    if (act) {
        #pragma unroll
        for (int i = 0; i < 6; ++i)
            #pragma unroll
            for (int j = 0; j < 8; ++j) acc[i][j] = 0.f;
        const float* z1p = Z + ((size_t)(BSZ + b)*NV)*ZLD + c0;
        const float* z2p = Z + ((size_t)(2*BSZ + b)*NV)*ZLD + c0;
        for (int m = 0; m < NV; ++m) {
            const float* ar = &smem[m*92 + n0];
            float2 a01 = *(const float2*)(ar);
            float2 a23 = *(const float2*)(ar + 2);
            float2 a45 = *(const float2*)(ar + 4);
            float av[6] = {a01.x, a01.y, a23.x, a23.y, a45.x, a45.y};
            const float4* z1r = (const float4*)(z1p + (size_t)m*ZLD);
            const float4* z2r = (const float4*)(z2p + (size_t)m*ZLD);
            float4 z1a = z1r[0], z1b = z1r[1];
            float4 z2a = z2r[0], z2b = z2r[1];
            float zv1[8] = {z1a.x,z1a.y,z1a.z,z1a.w,z1b.x,z1b.y,z1b.z,z1b.w};
            float zv2[8] = {z2a.x,z2a.y,z2a.z,z2a.w,z2b.x,z2b.y,z2b.z,z2b.w};
            #pragma unroll
            for (int i = 0; i < 6; ++i) {
                float a = av[i], bb = 2.f*a*a;
                #pragma unroll
                for (int j = 0; j < 8; ++j) acc[i][j] += a*zv1[j] + bb*zv2[j];
            }
        }
    }
    __syncthreads();                      // A region dead

    // epilogue: + Z0 - Z2, relu, write h tile into LDS (overlays A)
    float (*hl)[NV][CH] = (float (*)[NV][CH])smem;
    if (act) {
        const float* z0p = Z + ((size_t)b*NV)*ZLD;
        const float* z2p = Z + ((size_t)(2*BSZ + b)*NV)*ZLD;
        #pragma unroll
        for (int i = 0; i < 6; ++i) {
            int n = n0 + i;
            const float4* z0r = (const float4*)(z0p + (size_t)n*ZLD + c0);
            const float4* z2r = (const float4*)(z2p + (size_t)n*ZLD + c0);
            float4 z0a = z0r[0], z0b = z0r[1];
            float4 w2a = z2r[0], w2b = z2r[1];
            float zv0[8] = {z0a.x,z0a.y,z0a.z,z0a.w,z0b.x,z0b.y,z0b.z,z0b.w};
            float zv2[8] = {w2a.x,w2a.y,w2a.z,w2a.w,w2b.x,w2b.y,w2b.z,w2b.w};
            #pragma unroll
            for (int j = 0; j < 8; ++j) {
                int c = c0 + j;
                if (c < CCOL) {
                    float v = fmaxf(acc[i][j] + zv0[j] - zv2[j], 0.f);
                    hl[c/CH][n][c - (c/CH)*CH] = v;
                }
            }
        }
    }
    __syncthreads();

    // conv: groups of 4 horizontal pixels; 88 rows x 11 groups = 968
    const float cs  = csum[b];
    const float obv = ob[0];
    float* Xo = X + (size_t)b*FLATD + (size_t)t*FEAT;
    for (int g = tid; g < 88*11; g += TPB) {
        int i = g / 11, jg = g - (g/11)*11, j0 = 4*jg;
        float cf[10][4];
        #pragma unroll
        for (int f = 0; f < 10; ++f) {
            float bv = tb[f];
            cf[f][0] = bv; cf[f][1] = bv; cf[f][2] = bv; cf[f][3] = bv;
        }
        #pragma unroll
        for (int tp = 0; tp < 3; ++tp)
            #pragma unroll
            for (int di = 0; di < 3; ++di) {
                const float* hr = &hl[tp][i + di][j0];
                float w0 = hr[0], w1 = hr[1], w2 = hr[2],
                      w3 = hr[3], w4 = hr[4], w5 = hr[5];
                #pragma unroll
                for (int f = 0; f < 10; ++f) {
                    const float* twp = tw + ((f*TL + tp)*3 + di)*3;
                    float t0 = twp[0], t1 = twp[1], t2 = twp[2];
                    cf[f][0] += w0*t0 + w1*t1 + w2*t2;
                    cf[f][1] += w1*t0 + w2*t1 + w3*t2;
                    cf[f][2] += w2*t0 + w3*t1 + w4*t2;
                    cf[f][3] += w3*t0 + w4*t1 + w5*t2;
                }
            }
        float a0 = 0.f, a1 = 0.f, a2 = 0.f, a3 = 0.f;
        #pragma unroll
        for (int f = 0; f < 10; ++f) {
            float o = ow[f];
            a0 += fmaxf(cf[f][0], 0.f)*o; a1 += fmaxf(cf[f][1], 0.f)*o;
            a2 += fmaxf(cf[f][2], 0.f)*o; a3 += fmaxf(cf[f][3], 0.f)*o;
        }
        int pixb = i*CONV_W + j0;
        Xo[pixb] = (a0 + obv)*cs;
        if (j0 + 1 < CONV_W) Xo[pixb+1] = (a1 + obv)*cs;
        if (j0 + 2 < CONV_W) Xo[pixb+2] = (a2 + obv)*cs;
        if (j0 + 3 < CONV_W) Xo[pixb+3] = (a3 + obv)*cs;
    }
}

// ---------------- FC collapse: M = W2 D2 W3 ; Ma = D1 M ----------------
__global__ void k_eff1(const float* __restrict__ W2, const float* __restrict__ g2,
                       const float* __restrict__ W3, const float* __restrict__ g1,
                       float* __restrict__ M, float* __restrict__ Ma)
{
    int gid = blockIdx.x*TPB + threadIdx.x;
    if (gid >= 2048) return;
    int i = gid >> 1, c = gid & 1;
    const float rs = rsqrtf(1.f + 1e-5f);
    float acc = 0.f;
    for (int j = 0; j < 256; ++j) acc += W2[i*256 + j]*(g2[j]*rs)*W3[j*2 + c];
    M[gid]  = acc;
    Ma[gid] = acc*(g1[i]*rs);
}

__global__ void k_effb(const float* __restrict__ M, const float* __restrict__ W3,
                       const float* __restrict__ b1, const float* __restrict__ bb1, const float* __restrict__ g1,
                       const float* __restrict__ b2, const float* __restrict__ bb2, const float* __restrict__ g2,
                       const float* __restrict__ b3, float* __restrict__ beff)
{
    __shared__ float r0[TPB], r1[TPB];
    int tid = threadIdx.x;
    const float rs = rsqrtf(1.f + 1e-5f);
    float a0 = 0.f, a1 = 0.f;
    for (int i = tid; i < 1024; i += TPB) {
        float wv = b1[i]*(g1[i]*rs) + bb1[i];
        a0 += wv*M[2*i]; a1 += wv*M[2*i+1];
    }
    for (int j = tid; j < 256; j += TPB) {
        float wv = b2[j]*(g2[j]*rs) + bb2[j];
        a0 += wv*W3[2*j]; a1 += wv*W3[2*j+1];
    }
    r0[tid] = a0; r1[tid] = a1; __syncthreads();
    if (tid < 128) { r0[tid] += r0[tid+128]; r1[tid] += r1[tid+128]; } __syncthreads();
    if (tid < 64)  { r0[tid] += r0[tid+64];  r1[tid] += r1[tid+64];  } __syncthreads();
    if (tid < 64) {
        float x0 = r0[tid], x1 = r1[tid];
        #pragma unroll
        for (int o = 32; o >= 1; o >>= 1) { x0 += __shfl_down(x0, o); x1 += __shfl_down(x1, o); }
        if (tid == 0) { beff[0] = x0 + b3[0]; beff[1] = x1 + b3[1]; }
    }
}

// ---------------- Weff[r][c] = sum_i W1[r][i] * Ma[i][c]  (wave per row) ----------------
__global__ void k_eff2(const float* __restrict__ W1, const float* __restrict__ Ma,
                       float* __restrict__ Weff)
{
    int tid = threadIdx.x;
    int r = blockIdx.x*4 + (tid >> 6);
    int lane = tid & 63;
    if (r >= FLATD) return;
    const float* wrow = W1 + (size_t)r*1024;
    float a0 = 0.f, a1 = 0.f;
    for (int i = lane; i < 1024; i += 64) {
        float w = wrow[i];
        a0 += w*Ma[2*i]; a1 += w*Ma[2*i+1];
    }
    #pragma unroll
    for (int o = 32; o >= 1; o >>= 1) { a0 += __shfl_down(a0, o); a1 += __shfl_down(a1, o); }
    if (lane == 0) { Weff[2*r] = a0; Weff[2*r+1] = a1; }
}

// ---------------- logits + softmax ----------------
__global__ void k_logits(const float* __restrict__ x, const float* __restrict__ Weff,
                         const float* __restrict__ beff, float* __restrict__ out)
{
    __shared__ float r0[TPB], r1[TPB];
    int b = blockIdx.x, tid = threadIdx.x;
    const float* xr = x + (size_t)b*FLATD;
    float a0 = 0.f, a1 = 0.f;
    for (int i = tid; i < FLATD; i += TPB) {
        float v = xr[i];
        a0 += v*Weff[2*i]; a1 += v*Weff[2*i+1];
    }
    r0[tid] = a0; r1[tid] = a1; __syncthreads();
    if (tid < 128) { r0[tid] += r0[tid+128]; r1[tid] += r1[tid+128]; } __syncthreads();
    if (tid < 64)  { r0[tid] += r0[tid+64];  r1[tid] += r1[tid+64];  } __syncthreads();
    if (tid < 64) {
        float x0 = r0[tid], x1 = r1[tid];
        #pragma unroll
        for (int o = 32; o >= 1; o >>= 1) { x0 += __shfl_down(x0, o); x1 += __shfl_down(x1, o); }
        if (tid == 0) {
            float l0 = x0 + beff[0], l1 = x1 + beff[1];
            float mx = fmaxf(l0, l1);
            float e0 = expf(l0 - mx), e1 = expf(l1 - mx);
            float s = e0 + e1;
            out[2*b]     = e0/s;
            out[2*b + 1] = e1/s;
        }
    }
}

extern "C" void kernel_launch(void* const* d_in, const int* in_sizes, int n_in,
                              void* d_out, int out_size, void* d_ws, size_t ws_size,
                              hipStream_t stream)
{
    const float* fdata = (const float*)d_in[0];
    const float* un_w  = (const float*)d_in[1];
    const float* un_b  = (const float*)d_in[2];
    const float* theta = (const float*)d_in[3];
    const float* tcw   = (const float*)d_in[4];
    const float* tcb   = (const float*)d_in[5];
    const float* ocw   = (const float*)d_in[6];
    const float* ocb   = (const float*)d_in[7];
    const float* l1w   = (const float*)d_in[8];
    const float* l1b   = (const float*)d_in[9];
    const float* bn1g  = (const float*)d_in[10];
    const float* bn1b  = (const float*)d_in[11];
    const float* l2w   = (const float*)d_in[12];
    const float* l2b   = (const float*)d_in[13];
    const float* bn2g  = (const float*)d_in[14];
    const float* bn2b  = (const float*)d_in[15];
    const float* l3w   = (const float*)d_in[16];
    const float* l3b   = (const float*)d_in[17];

    float* ws   = (float*)d_ws;
    float* csum = ws + OFF_CSUM;
    float* lam  = ws + OFF_LAM;
    float* beff = ws + OFF_BEFF;
    float* M    = ws + OFF_M;
    float* Ma   = ws + OFF_MA;
    float* Weff = ws + OFF_WEFF;
    float* L    = ws + OFF_L;
    float* Z    = ws + OFF_Z;
    float* X    = ws + OFF_X;
    float* out  = (float*)d_out;

    hipMemsetAsync(csum, 0, BSZ*sizeof(float), stream);
    k_prep <<<NP, TPB, 0, stream>>>(fdata, un_w, un_b, L, lam, csum);
    k_Z    <<<BSZ*TL, TPB, 0, stream>>>(fdata, theta, Z);
    k_hc   <<<NP, TPB, 0, stream>>>(L, lam, Z, tcw, tcb, ocw, ocb, csum, X);
    k_eff1 <<<8, TPB, 0, stream>>>(l2w, bn2g, l3w, bn1g, M, Ma);
    k_effb <<<1, TPB, 0, stream>>>(M, l3w, l1b, bn1b, bn1g, l2b, bn2b, bn2g, l3b, beff);
    k_eff2 <<<(FLATD + 3)/4, TPB, 0, stream>>>(l1w, Ma, Weff);
    k_logits<<<BSZ, TPB, 0, stream>>>(X, Weff, beff, out);
}

// Round 4
// 512.473 us; speedup vs baseline: 1.8695x; 1.0887x over previous
//
#include <hip/hip_runtime.h>
#include <math.h>

#define TPB 256

// problem sizes
constexpr int BSZ = 256, TL = 3, NV = 90, SV = 65, CH = 45;
constexpr int NS = NV*SV;            // 5850
constexpr int NP = TL*BSZ;           // 768 (t,b) pairs, q = t*256+b
constexpr int NM = NV*NV;            // 8100
constexpr int CCOL = TL*CH;          // 135 combined (t',o) columns
constexpr int ZLD = 136;             // padded Z row stride
constexpr int CONV_H = 88, CONV_W = 43, FEAT = CONV_H*CONV_W; // 3784
constexpr int FLATD = TL*FEAT;       // 11352

// workspace layout (float offsets)
constexpr size_t OFF_CSUM = 0;
constexpr size_t OFF_LAM  = 256;
constexpr size_t OFF_BEFF = 1024;
constexpr size_t OFF_M    = 1056;
constexpr size_t OFF_MA   = 3104;
constexpr size_t OFF_WEFF = 5152;
constexpr size_t OFF_L    = 32768;                    // 768*8100
constexpr size_t OFF_Z    = 6291456;                  // 3*256*90*136
constexpr size_t OFF_X    = 15728640;                 // 256*11352

// ============================================================================
// k_corr: normalize rows -> yT (swizzled), pearson corr -> L (global),
// row sums via LDS atomics, uncertainty-head partial into csum.
// ============================================================================
__global__ __launch_bounds__(TPB) void k_corr(const float* __restrict__ fdata,
    const float* __restrict__ unw, const float* __restrict__ unb,
    float* __restrict__ Lout, float* __restrict__ csum)
{
    __shared__ float yT[65*96];      // 24,960 B
    __shared__ float Dl[NV], Wd[NV];
    __shared__ float red[TPB];

    const int q = blockIdx.x, tid = threadIdx.x;
    const int t = q >> 8, b = q & 255;
    const float* xp = fdata + ((size_t)b*TL + t)*NS;
    const int wave = tid >> 6, lane = tid & 63;

    if (tid < NV) Dl[tid] = 0.f;

    // ---- normalize + uncertainty partial ----
    float up = 0.f;
    for (int n = wave; n < NV; n += 4) {
        const float* row = xp + n*SV;
        float va = row[lane];
        float vb = (lane == 0) ? row[64] : 0.f;
        up += va*unw[n*SV + lane];
        if (lane == 0) up += vb*unw[n*SV + 64];
        float s1 = va + vb, s2 = va*va + vb*vb;
        #pragma unroll
        for (int o = 1; o < 64; o <<= 1) { s1 += __shfl_xor(s1, o); s2 += __shfl_xor(s2, o); }
        float mean = s1 / SV;
        float var  = s2 - SV*mean*mean;
        float inv  = 1.f / (sqrtf(fmaxf(var, 0.f)) + 1e-6f);
        yT[lane*96 + (((n >> 2) + lane) % 24)*4 + (n & 3)] = (va - mean)*inv;
        if (lane == 0)
            yT[64*96 + (((n >> 2) + 64) % 24)*4 + (n & 3)] = (vb - mean)*inv;
    }
    red[tid] = up; __syncthreads();
    if (tid < 128) red[tid] += red[tid+128]; __syncthreads();
    if (tid < 64)  red[tid] += red[tid+64];  __syncthreads();
    if (tid < 64) {
        float x = red[tid];
        #pragma unroll
        for (int o = 32; o >= 1; o >>= 1) x += __shfl_down(x, o);
        if (tid == 0) {
            float u = x + unb[0];
            atomicAdd(csum + (q/3), 1.f/(1.f + expf(-u)));
        }
    }
    __syncthreads();

    // ---- corr tiles -> W -> off-diag L stores + row-sum atomics ----
    float* Lq = Lout + (size_t)q*NM;
    for (int tile = tid; tile < 529; tile += TPB) {     // 23x23 tiles of 4x4
        int tr = tile / 23, tc = tile - tr*23;
        int n0 = 4*tr, m0 = 4*tc;
        int ca = tr, cb = tc;
        float acc[4][4] = {};
        for (int s = 0; s < SV; ++s) {
            const float* base = &yT[s*96];
            float4 a4 = *(const float4*)(base + 4*ca);
            float4 b4 = *(const float4*)(base + 4*cb);
            float av[4] = {a4.x, a4.y, a4.z, a4.w};
            float bv[4] = {b4.x, b4.y, b4.z, b4.w};
            #pragma unroll
            for (int i = 0; i < 4; ++i)
                #pragma unroll
                for (int j = 0; j < 4; ++j) acc[i][j] += av[i]*bv[j];
            if (++ca == 24) ca = 0;
            if (++cb == 24) cb = 0;
        }
        #pragma unroll
        for (int i = 0; i < 4; ++i) {
            int n = n0 + i;
            if (n >= NV) break;
            float rsum = 0.f;
            #pragma unroll
            for (int j = 0; j < 4; ++j) {
                int m = m0 + j;
                if (m < NV) {
                    float w = (acc[i][j] + 1.f)*0.5f;
                    rsum += w;
                    if (n != m) Lq[n*NV + m] = -w;
                    else        Wd[n] = w;
                }
            }
            atomicAdd(&Dl[n], rsum);
        }
    }
    __syncthreads();
    if (tid < NV) Lq[tid*(NV+1)] = Dl[tid] - Wd[tid];
}

// ============================================================================
// k_eig: one wave per q. Lane owns rows {lane, 64+lane} in registers; v shared
// via per-wave LDS; renorm/Rayleigh via shuffles. Shifted power iteration.
// ============================================================================
__global__ __launch_bounds__(TPB) void k_eig(const float* __restrict__ L,
                                             float* __restrict__ lamOut)
{
    __shared__ float vbuf[4][2][92];
    const int tid = threadIdx.x, w = tid >> 6, lane = tid & 63;
    const int q = blockIdx.x*4 + w;
    const float* Lq = L + (size_t)q*NM;

    float LA[92], LB[92];
    {
        const float2* ra = (const float2*)(Lq + lane*NV);
        #pragma unroll
        for (int j = 0; j < 45; ++j) { float2 x = ra[j]; LA[2*j] = x.x; LA[2*j+1] = x.y; }
        LA[90] = 0.f; LA[91] = 0.f;
        if (lane < 26) {
            const float2* rb = (const float2*)(Lq + (64 + lane)*NV);
            #pragma unroll
            for (int j = 0; j < 45; ++j) { float2 x = rb[j]; LB[2*j] = x.x; LB[2*j+1] = x.y; }
        } else {
            #pragma unroll
            for (int j = 0; j < 90; ++j) LB[j] = 0.f;
        }
        LB[90] = 0.f; LB[91] = 0.f;
    }
    if (lane < 2) { vbuf[w][0][90+lane] = 0.f; vbuf[w][1][90+lane] = 0.f; }

    float vA = sinf(1.3f*lane + 0.5f) + 0.05f;
    float vB = (lane < 26) ? (sinf(1.3f*(64 + lane) + 0.5f) + 0.05f) : 0.f;
    int cur = 0;
    float wA = 0.f, wB = 0.f;

    auto share = [&]() {
        vbuf[w][cur][lane] = vA;
        if (lane < 26) vbuf[w][cur][64 + lane] = vB;
        __syncthreads();
    };
    auto matvec = [&](float sigma) {
        const float4* v4 = (const float4*)&vbuf[w][cur][0];
        float p0=0.f,p1=0.f,p2=0.f,p3=0.f, r0=0.f,r1=0.f,r2=0.f,r3=0.f;
        #pragma unroll
        for (int j = 0; j < 23; ++j) {
            float4 x = v4[j];
            p0 += LA[4*j]*x.x;   p1 += LA[4*j+1]*x.y;
            p2 += LA[4*j+2]*x.z; p3 += LA[4*j+3]*x.w;
            r0 += LB[4*j]*x.x;   r1 += LB[4*j+1]*x.y;
            r2 += LB[4*j+2]*x.z; r3 += LB[4*j+3]*x.w;
        }
        wA = (p0+p1) + (p2+p3) - sigma*vA;
        wB = (r0+r1) + (r2+r3) - sigma*vB;
        cur ^= 1;
    };
    auto renorm = [&]() {
        float t1 = vA + ((lane < 26) ? vB : 0.f);
        float t2 = vA*vA + ((lane < 26) ? vB*vB : 0.f);
        #pragma unroll
        for (int o = 1; o < 64; o <<= 1) { t1 += __shfl_xor(t1, o); t2 += __shfl_xor(t2, o); }
        float mean = t1*(1.f/90.f);
        float ns   = t2 - 90.f*mean*mean;
        float rn   = rsqrtf(fmaxf(ns, 1e-30f));
        vA = (vA - mean)*rn; vB = (vB - mean)*rn;
    };
    auto dotvw = [&]() {
        float d = vA*wA + ((lane < 26) ? vB*wB : 0.f);
        #pragma unroll
        for (int o = 1; o < 64; o <<= 1) d += __shfl_xor(d, o);
        return d;
    };

    for (int it = 0; it < 8; ++it) { share(); matvec(0.f); vA = wA; vB = wB; }
    renorm();
    share(); matvec(0.f);
    float ray = dotvw();
    float sigma = 0.45f*ray;
    vA = wA - sigma*vA; vB = wB - sigma*vB;
    for (int it = 0; it < 87; ++it) {
        if ((it & 7) == 7) renorm();
        share(); matvec(sigma); vA = wA; vB = wB;
    }
    renorm();
    share(); matvec(0.f);
    float lam = dotvw();
    if (lane == 0) lamOut[q] = lam;
}

// ============================================================================
// k_Z: Z[k][b][m][tp*45+o] = sum_s fdata[b,tp,m,s] * theta[k,s,o]
// coalesced row-major staging; broadcast-friendly tile mapping.
// ============================================================================
__global__ __launch_bounds__(TPB) void k_Z(const float* __restrict__ fdata,
                                           const float* __restrict__ theta,
                                           float* __restrict__ Z)
{
    __shared__ float fl[NV][69];          // 24,840 B, coalesced staged
    __shared__ float thl[3][SV][48];      // 37,440 B, o padded to 48 (zeros)

    const int g = blockIdx.x, tid = threadIdx.x;
    const int b = g/3, tp = g - 3*b;
    const float* fp = fdata + ((size_t)b*TL + tp)*NS;

    for (int idx = tid; idx < NS; idx += TPB) {
        int m = idx / SV, s = idx - m*SV;
        fl[m][s] = fp[idx];
    }
    for (int idx = tid; idx < 3*SV*48; idx += TPB) {
        int k = idx / (SV*48), rr = idx - k*(SV*48);
        int s = rr / 48, o = rr - s*48;
        thl[k][s][o] = (o < CH) ? theta[(k*SV + s)*CH + o] : 0.f;
    }
    __syncthreads();

    // 23 m-tiles (4 rows) x 18 (k,ot) col-tiles (8 cols) = 414 tiles
    for (int tile = tid; tile < 414; tile += TPB) {
        int mt = tile / 18, ct = tile - mt*18;       // consecutive lanes share mt
        int k = ct / 6, ot = ct - 6*k;
        int m0 = 4*mt, o0 = 8*ot;
        float acc[4][8] = {};
        for (int s = 0; s < SV; ++s) {
            float a0 = fl[m0][s], a1 = fl[m0+1][s], a2 = fl[m0+2][s], a3 = fl[m0+3][s];
            float4 t0 = *(const float4*)&thl[k][s][o0];
            float4 t1 = *(const float4*)&thl[k][s][o0+4];
            float tv[8] = {t0.x,t0.y,t0.z,t0.w,t1.x,t1.y,t1.z,t1.w};
            #pragma unroll
            for (int j = 0; j < 8; ++j) {
                acc[0][j] += a0*tv[j]; acc[1][j] += a1*tv[j];
                acc[2][j] += a2*tv[j]; acc[3][j] += a3*tv[j];
            }
        }
        #pragma unroll
        for (int i = 0; i < 4; ++i) {
            int m = m0 + i; if (m >= NV) break;
            float* zp = Z + ((size_t)(k*BSZ + b)*NV + m)*ZLD + tp*CH;
            #pragma unroll
            for (int j = 0; j < 8; ++j) {
                int o = o0 + j;
                if (o < CH) zp[o] = acc[i][j];
            }
        }
    }
    if (tp == 2) {    // zero pad col 135
        for (int idx = tid; idx < 3*NV; idx += TPB) {
            int k = idx / NV, m = idx - k*NV;
            Z[((size_t)(k*BSZ + b)*NV + m)*ZLD + 135] = 0.f;
        }
    }
}

// ============================================================================
// k_hc: fused  h = relu(Z0 + Lt@Z1 + (2Lt^2)@Z2 - Z2)  ->  3x3x3 conv -> relu
//       -> 1x1 conv -> *csum -> X.   Lt built on the fly from L and lambda.
// ============================================================================
__global__ __launch_bounds__(TPB) void k_hc(const float* __restrict__ L,
    const float* __restrict__ lam, const float* __restrict__ Z,
    const float* __restrict__ tw, const float* __restrict__ tb,
    const float* __restrict__ ow, const float* __restrict__ ob,
    const float* __restrict__ csum, float* __restrict__ X)
{
    __shared__ float smem[12160];        // 48,640 B
    const int q = blockIdx.x, tid = threadIdx.x;
    const int t = q >> 8, b = q & 255;
    const float il2 = 2.0f / lam[q];

    for (int idx = tid; idx < NM; idx += TPB) {
        int i = idx / NV, j = idx - i*NV;
        smem[i*92 + j] = il2 * L[(size_t)q*NM + idx] - ((i == j) ? 1.f : 0.f);
    }
    __syncthreads();

    float acc[6][8];
    const int tn = tid / 17, tc = tid - tn*17;
    const int n0 = 6*tn, c0 = 8*tc;
    const bool act = (tid < 255);
    if (act) {
        #pragma unroll
        for (int i = 0; i < 6; ++i)
            #pragma unroll
            for (int j = 0; j < 8; ++j) acc[i][j] = 0.f;
        const float* z1p = Z + ((size_t)(BSZ + b)*NV)*ZLD + c0;
        const float* z2p = Z + ((size_t)(2*BSZ + b)*NV)*ZLD + c0;
        for (int m = 0; m < NV; ++m) {
            const float* ar = &smem[m*92 + n0];
            float2 a01 = *(const float2*)(ar);
            float2 a23 = *(const float2*)(ar + 2);
            float2 a45 = *(const float2*)(ar + 4);
            float av[6] = {a01.x, a01.y, a23.x, a23.y, a45.x, a45.y};
            const float4* z1r = (const float4*)(z1p + (size_t)m*ZLD);
            const float4* z2r = (const float4*)(z2p + (size_t)m*ZLD);
            float4 z1a = z1r[0], z1b = z1r[1];
            float4 z2a = z2r[0], z2b = z2r[1];
            float zv1[8] = {z1a.x,z1a.y,z1a.z,z1a.w,z1b.x,z1b.y,z1b.z,z1b.w};
            float zv2[8] = {z2a.x,z2a.y,z2a.z,z2a.w,z2b.x,z2b.y,z2b.z,z2b.w};
            #pragma unroll
            for (int i = 0; i < 6; ++i) {
                float a = av[i], bb = 2.f*a*a;
                #pragma unroll
                for (int j = 0; j < 8; ++j) acc[i][j] += a*zv1[j] + bb*zv2[j];
            }
        }
    }
    __syncthreads();

    float (*hl)[NV][CH] = (float (*)[NV][CH])smem;
    if (act) {
        const float* z0p = Z + ((size_t)b*NV)*ZLD;
        const float* z2p = Z + ((size_t)(2*BSZ + b)*NV)*ZLD;
        #pragma unroll
        for (int i = 0; i < 6; ++i) {
            int n = n0 + i;
            const float4* z0r = (const float4*)(z0p + (size_t)n*ZLD + c0);
            const float4* z2r = (const float4*)(z2p + (size_t)n*ZLD + c0);
            float4 z0a = z0r[0], z0b = z0r[1];
            float4 w2a = z2r[0], w2b = z2r[1];
            float zv0[8] = {z0a.x,z0a.y,z0a.z,z0a.w,z0b.x,z0b.y,z0b.z,z0b.w};
            float zv2[8] = {w2a.x,w2a.y,w2a.z,w2a.w,w2b.x,w2b.y,w2b.z,w2b.w};
            #pragma unroll
            for (int j = 0; j < 8; ++j) {
                int c = c0 + j;
                if (c < CCOL) {
                    float v = fmaxf(acc[i][j] + zv0[j] - zv2[j], 0.f);
                    hl[c/CH][n][c - (c/CH)*CH] = v;
                }
            }
        }
    }
    __syncthreads();

    const float cs  = csum[b];
    const float obv = ob[0];
    float* Xo = X + (size_t)b*FLATD + (size_t)t*FEAT;
    for (int g = tid; g < 88*11; g += TPB) {
        int i = g / 11, jg = g - (g/11)*11, j0 = 4*jg;
        float cf[10][4];
        #pragma unroll
        for (int f = 0; f < 10; ++f) {
            float bv = tb[f];
            cf[f][0] = bv; cf[f][1] = bv; cf[f][2] = bv; cf[f][3] = bv;
        }
        #pragma unroll
        for (int tp = 0; tp < 3; ++tp)
            #pragma unroll
            for (int di = 0; di < 3; ++di) {
                const float* hr = &hl[tp][i + di][j0];
                float w0 = hr[0], w1 = hr[1], w2 = hr[2],
                      w3 = hr[3], w4 = hr[4], w5 = hr[5];
                #pragma unroll
                for (int f = 0; f < 10; ++f) {
                    const float* twp = tw + ((f*TL + tp)*3 + di)*3;
                    float t0 = twp[0], t1 = twp[1], t2 = twp[2];
                    cf[f][0] += w0*t0 + w1*t1 + w2*t2;
                    cf[f][1] += w1*t0 + w2*t1 + w3*t2;
                    cf[f][2] += w2*t0 + w3*t1 + w4*t2;
                    cf[f][3] += w3*t0 + w4*t1 + w5*t2;
                }
            }
        float a0 = 0.f, a1 = 0.f, a2 = 0.f, a3 = 0.f;
        #pragma unroll
        for (int f = 0; f < 10; ++f) {
            float o = ow[f];
            a0 += fmaxf(cf[f][0], 0.f)*o; a1 += fmaxf(cf[f][1], 0.f)*o;
            a2 += fmaxf(cf[f][2], 0.f)*o; a3 += fmaxf(cf[f][3], 0.f)*o;
        }
        int pixb = i*CONV_W + j0;
        Xo[pixb] = (a0 + obv)*cs;
        if (j0 + 1 < CONV_W) Xo[pixb+1] = (a1 + obv)*cs;
        if (j0 + 2 < CONV_W) Xo[pixb+2] = (a2 + obv)*cs;
        if (j0 + 3 < CONV_W) Xo[pixb+3] = (a3 + obv)*cs;
    }
}

// ---------------- FC collapse ----------------
__global__ void k_eff1(const float* __restrict__ W2, const float* __restrict__ g2,
                       const float* __restrict__ W3, const float* __restrict__ g1,
                       float* __restrict__ M, float* __restrict__ Ma)
{
    int gid = blockIdx.x*TPB + threadIdx.x;
    if (gid >= 2048) return;
    int i = gid >> 1, c = gid & 1;
    const float rs = rsqrtf(1.f + 1e-5f);
    float acc = 0.f;
    for (int j = 0; j < 256; ++j) acc += W2[i*256 + j]*(g2[j]*rs)*W3[j*2 + c];
    M[gid]  = acc;
    Ma[gid] = acc*(g1[i]*rs);
}

__global__ void k_effb(const float* __restrict__ M, const float* __restrict__ W3,
                       const float* __restrict__ b1, const float* __restrict__ bb1, const float* __restrict__ g1,
                       const float* __restrict__ b2, const float* __restrict__ bb2, const float* __restrict__ g2,
                       const float* __restrict__ b3, float* __restrict__ beff)
{
    __shared__ float r0[TPB], r1[TPB];
    int tid = threadIdx.x;
    const float rs = rsqrtf(1.f + 1e-5f);
    float a0 = 0.f, a1 = 0.f;
    for (int i = tid; i < 1024; i += TPB) {
        float wv = b1[i]*(g1[i]*rs) + bb1[i];
        a0 += wv*M[2*i]; a1 += wv*M[2*i+1];
    }
    for (int j = tid; j < 256; j += TPB) {
        float wv = b2[j]*(g2[j]*rs) + bb2[j];
        a0 += wv*W3[2*j]; a1 += wv*W3[2*j+1];
    }
    r0[tid] = a0; r1[tid] = a1; __syncthreads();
    if (tid < 128) { r0[tid] += r0[tid+128]; r1[tid] += r1[tid+128]; } __syncthreads();
    if (tid < 64)  { r0[tid] += r0[tid+64];  r1[tid] += r1[tid+64];  } __syncthreads();
    if (tid < 64) {
        float x0 = r0[tid], x1 = r1[tid];
        #pragma unroll
        for (int o = 32; o >= 1; o >>= 1) { x0 += __shfl_down(x0, o); x1 += __shfl_down(x1, o); }
        if (tid == 0) { beff[0] = x0 + b3[0]; beff[1] = x1 + b3[1]; }
    }
}

__global__ void k_eff2(const float* __restrict__ W1, const float* __restrict__ Ma,
                       float* __restrict__ Weff)
{
    int tid = threadIdx.x;
    int r = blockIdx.x*4 + (tid >> 6);
    int lane = tid & 63;
    if (r >= FLATD) return;
    const float* wrow = W1 + (size_t)r*1024;
    float a0 = 0.f, a1 = 0.f;
    for (int i = lane; i < 1024; i += 64) {
        float w = wrow[i];
        a0 += w*Ma[2*i]; a1 += w*Ma[2*i+1];
    }
    #pragma unroll
    for (int o = 32; o >= 1; o >>= 1) { a0 += __shfl_down(a0, o); a1 += __shfl_down(a1, o); }
    if (lane == 0) { Weff[2*r] = a0; Weff[2*r+1] = a1; }
}

__global__ void k_logits(const float* __restrict__ x, const float* __restrict__ Weff,
                         const float* __restrict__ beff, float* __restrict__ out)
{
    __shared__ float r0[TPB], r1[TPB];
    int b = blockIdx.x, tid = threadIdx.x;
    const float* xr = x + (size_t)b*FLATD;
    float a0 = 0.f, a1 = 0.f;
    for (int i = tid; i < FLATD; i += TPB) {
        float v = xr[i];
        a0 += v*Weff[2*i]; a1 += v*Weff[2*i+1];
    }
    r0[tid] = a0; r1[tid] = a1; __syncthreads();
    if (tid < 128) { r0[tid] += r0[tid+128]; r1[tid] += r1[tid+128]; } __syncthreads();
    if (tid < 64)  { r0[tid] += r0[tid+64];  r1[tid] += r1[tid+64];  } __syncthreads();
    if (tid < 64) {
        float x0 = r0[tid], x1 = r1[tid];
        #pragma unroll
        for (int o = 32; o >= 1; o >>= 1) { x0 += __shfl_down(x0, o); x1 += __shfl_down(x1, o); }
        if (tid == 0) {
            float l0 = x0 + beff[0], l1 = x1 + beff[1];
            float mx = fmaxf(l0, l1);
            float e0 = expf(l0 - mx), e1 = expf(l1 - mx);
            float s = e0 + e1;
            out[2*b]     = e0/s;
            out[2*b + 1] = e1/s;
        }
    }
}

extern "C" void kernel_launch(void* const* d_in, const int* in_sizes, int n_in,
                              void* d_out, int out_size, void* d_ws, size_t ws_size,
                              hipStream_t stream)
{
    const float* fdata = (const float*)d_in[0];
    const float* un_w  = (const float*)d_in[1];
    const float* un_b  = (const float*)d_in[2];
    const float* theta = (const float*)d_in[3];
    const float* tcw   = (const float*)d_in[4];
    const float* tcb   = (const float*)d_in[5];
    const float* ocw   = (const float*)d_in[6];
    const float* ocb   = (const float*)d_in[7];
    const float* l1w   = (const float*)d_in[8];
    const float* l1b   = (const float*)d_in[9];
    const float* bn1g  = (const float*)d_in[10];
    const float* bn1b  = (const float*)d_in[11];
    const float* l2w   = (const float*)d_in[12];
    const float* l2b   = (const float*)d_in[13];
    const float* bn2g  = (const float*)d_in[14];
    const float* bn2b  = (const float*)d_in[15];
    const float* l3w   = (const float*)d_in[16];
    const float* l3b   = (const float*)d_in[17];

    float* ws   = (float*)d_ws;
    float* csum = ws + OFF_CSUM;
    float* lam  = ws + OFF_LAM;
    float* beff = ws + OFF_BEFF;
    float* M    = ws + OFF_M;
    float* Ma   = ws + OFF_MA;
    float* Weff = ws + OFF_WEFF;
    float* L    = ws + OFF_L;
    float* Z    = ws + OFF_Z;
    float* X    = ws + OFF_X;
    float* out  = (float*)d_out;

    hipMemsetAsync(csum, 0, BSZ*sizeof(float), stream);
    k_corr <<<NP, TPB, 0, stream>>>(fdata, un_w, un_b, L, csum);
    k_eig  <<<NP/4, TPB, 0, stream>>>(L, lam);
    k_Z    <<<BSZ*TL, TPB, 0, stream>>>(fdata, theta, Z);
    k_hc   <<<NP, TPB, 0, stream>>>(L, lam, Z, tcw, tcb, ocw, ocb, csum, X);
    k_eff1 <<<8, TPB, 0, stream>>>(l2w, bn2g, l3w, bn1g, M, Ma);
    k_effb <<<1, TPB, 0, stream>>>(M, l3w, l1b, bn1b, bn1g, l2b, bn2b, bn2g, l3b, beff);
    k_eff2 <<<(FLATD + 3)/4, TPB, 0, stream>>>(l1w, Ma, Weff);
    k_logits<<<BSZ, TPB, 0, stream>>>(X, Weff, beff, out);
}